// Round 1
// 15172.734 us; speedup vs baseline: 1.9767x; 1.9767x over previous
//
#include <hip/hip_runtime.h>
#include <stdint.h>

#define DIM   1024
#define TLEN  1024
#define BATCH 32
#define NCODE 256

// ws layout in floats
#define WS_CC   16
#define WS_IDX  272
#define WS_CGI  33040
#define WS_H    819472
#define WS_HP   34373904

#define OUT_IDX 33554432
#define OUT_TOT 33587200

// ---------------- codebook norms ----------------
__global__ __launch_bounds__(256) void k_norms(const float* __restrict__ cb,
                                               float* __restrict__ cc) {
  int c = blockIdx.x;
  int t = threadIdx.x;
  const float4* p = (const float4*)(cb + (size_t)c * DIM);
  float4 v = p[t];
  float s = v.x*v.x + v.y*v.y + v.z*v.z + v.w*v.w;
#pragma unroll
  for (int m = 1; m < 64; m <<= 1) s += __shfl_xor(s, m);
  __shared__ float ls[4];
  if ((t & 63) == 0) ls[t >> 6] = s;
  __syncthreads();
  if (t == 0) cc[c] = ls[0] + ls[1] + ls[2] + ls[3];
}

// ---------------- quantize: scores + argmin + outputs + sse ----------------
__global__ __launch_bounds__(256) void k_quant(
    const float* __restrict__ F, const float* __restrict__ CB,
    const float* __restrict__ cc, float* __restrict__ qout,
    float* __restrict__ idxf, int* __restrict__ idxi,
    float* __restrict__ sse_acc)
{
  __shared__ float Fl[32][33];
  __shared__ float Cl[256][33];
  __shared__ float ccl[256];
  __shared__ float sumff[32];
  __shared__ unsigned long long rowmin[32];
  __shared__ float wsum[4];

  const int tid = threadIdx.x;
  const size_t m0 = (size_t)blockIdx.x * 32;

  const int tm = tid >> 5;   // 0..7   rows r = tm + 8i
  const int tn = tid & 31;   // 0..31  codes c = tn + 32j
  const int ar = tid >> 3;   // 0..31  staging row
  const int ac = tid & 7;    // 0..7   staging float4 idx

  if (tid < 32) rowmin[tid] = ~0ull;
  ccl[tid] = cc[tid];

  float acc[4][8];
#pragma unroll
  for (int i = 0; i < 4; ++i)
#pragma unroll
    for (int j = 0; j < 8; ++j) acc[i][j] = 0.f;
  float ffp = 0.f;

  for (int k0 = 0; k0 < DIM; k0 += 32) {
    __syncthreads();
    {
      float4 v = *(const float4*)&F[(m0 + ar) * DIM + k0 + 4 * ac];
      Fl[ar][4*ac+0] = v.x; Fl[ar][4*ac+1] = v.y;
      Fl[ar][4*ac+2] = v.z; Fl[ar][4*ac+3] = v.w;
      ffp += v.x*v.x + v.y*v.y + v.z*v.z + v.w*v.w;
    }
#pragma unroll
    for (int rep = 0; rep < 8; ++rep) {
      int r = ar + 32 * rep;
      float4 v = *(const float4*)&CB[(size_t)r * DIM + k0 + 4 * ac];
      Cl[r][4*ac+0] = v.x; Cl[r][4*ac+1] = v.y;
      Cl[r][4*ac+2] = v.z; Cl[r][4*ac+3] = v.w;
    }
    __syncthreads();
    for (int kk = 0; kk < 32; ++kk) {
      float a[4], b[8];
#pragma unroll
      for (int i = 0; i < 4; ++i) a[i] = Fl[tm + 8*i][kk];
#pragma unroll
      for (int j = 0; j < 8; ++j) b[j] = Cl[tn + 32*j][kk];
#pragma unroll
      for (int i = 0; i < 4; ++i)
#pragma unroll
        for (int j = 0; j < 8; ++j) acc[i][j] += a[i] * b[j];
    }
  }
  {
    float s = ffp;
    s += __shfl_xor(s, 1); s += __shfl_xor(s, 2); s += __shfl_xor(s, 4);
    if (ac == 0) sumff[ar] = s;
  }
  __syncthreads();
#pragma unroll
  for (int i = 0; i < 4; ++i) {
    float sf = sumff[tm + 8*i];
    unsigned long long best = ~0ull;
#pragma unroll
    for (int j = 0; j < 8; ++j) {
      int c = tn + 32*j;
      float sc = (sf - 2.f * acc[i][j]) + ccl[c];   // mimic ref rounding order
      unsigned ub = __float_as_uint(sc);
      ub = (ub & 0x80000000u) ? ~ub : (ub | 0x80000000u);
      unsigned long long key = ((unsigned long long)ub << 32) | (unsigned)c;
      if (key < best) best = key;
    }
    atomicMin(&rowmin[tm + 8*i], best);
  }
  __syncthreads();
  if (tid < 32) {
    int code = (int)(rowmin[tid] & 0xffffffffull);
    idxi[m0 + tid] = code;
    idxf[m0 + tid] = (float)code;
  }
  float ssep = 0.f;
  for (int r = 0; r < 32; ++r) {
    int code = (int)(rowmin[r] & 0xffffffffull);
    float4 q = *(const float4*)&CB[(size_t)code * DIM + 4 * tid];
    float4 f = *(const float4*)&F[(m0 + r) * DIM + 4 * tid];
    *(float4*)&qout[(m0 + r) * DIM + 4 * tid] = q;
    float dx = f.x-q.x, dy = f.y-q.y, dz = f.z-q.z, dw = f.w-q.w;
    ssep += dx*dx + dy*dy + dz*dz + dw*dw;
  }
  {
    float s = ssep;
#pragma unroll
    for (int m = 1; m < 64; m <<= 1) s += __shfl_xor(s, m);
    if ((tid & 63) == 0) wsum[tid >> 6] = s;
  }
  __syncthreads();
  if (tid == 0) atomicAdd(sse_acc, wsum[0] + wsum[1] + wsum[2] + wsum[3]);
}

// ---------------- generic NT GEMM: C[M,N] = A[M,K] * B[N,K]^T + bias ----------------
template<int BM, int BN, int BK>
__global__ __launch_bounds__(256) void k_gemm_nt(
    const float* __restrict__ A, const float* __restrict__ B,
    const float* __restrict__ bias, float* __restrict__ C,
    int M, int N, int K)
{
  __shared__ float Al[BM][BK + 1];
  __shared__ float Bl[BN][BK + 1];
  const int tid = threadIdx.x;
  const int tm = tid >> 4;   // 0..15
  const int tn = tid & 15;   // 0..15
  const size_t m0 = (size_t)blockIdx.y * BM;
  const size_t n0 = (size_t)blockIdx.x * BN;
  float acc[BM/16][BN/16];
#pragma unroll
  for (int i = 0; i < BM/16; ++i)
#pragma unroll
    for (int j = 0; j < BN/16; ++j) acc[i][j] = 0.f;

  constexpr int F4R = BK / 4;
  for (int k0 = 0; k0 < K; k0 += BK) {
    __syncthreads();
    for (int rr = tid; rr < BM * F4R; rr += 256) {
      int r = rr / F4R, c4 = rr % F4R;
      float4 v = *(const float4*)&A[(m0 + r) * K + k0 + 4 * c4];
      Al[r][4*c4+0] = v.x; Al[r][4*c4+1] = v.y;
      Al[r][4*c4+2] = v.z; Al[r][4*c4+3] = v.w;
    }
    for (int rr = tid; rr < BN * F4R; rr += 256) {
      int r = rr / F4R, c4 = rr % F4R;
      float4 v = *(const float4*)&B[(n0 + r) * K + k0 + 4 * c4];
      Bl[r][4*c4+0] = v.x; Bl[r][4*c4+1] = v.y;
      Bl[r][4*c4+2] = v.z; Bl[r][4*c4+3] = v.w;
    }
    __syncthreads();
    for (int kk = 0; kk < BK; ++kk) {
      float a[BM/16], b[BN/16];
#pragma unroll
      for (int i = 0; i < BM/16; ++i) a[i] = Al[tm + 16*i][kk];
#pragma unroll
      for (int j = 0; j < BN/16; ++j) b[j] = Bl[tn + 16*j][kk];
#pragma unroll
      for (int i = 0; i < BM/16; ++i)
#pragma unroll
        for (int j = 0; j < BN/16; ++j) acc[i][j] += a[i] * b[j];
    }
  }
#pragma unroll
  for (int i = 0; i < BM/16; ++i)
#pragma unroll
    for (int j = 0; j < BN/16; ++j) {
      size_t cn = n0 + tn + 16*j;
      C[(m0 + tm + 16*i) * N + cn] = acc[i][j] + bias[cn];
    }
}

// ---------------- persistent GRU (grouped, register weights, scan barrier) ---
// 256 blocks x 1024 threads = 4 groups x 64 blocks.
// group g owns batches [8g, 8g+8); block member m owns dims [16m, 16m+16);
// wave w owns dim d = 16m + w and holds its 3 gate rows of Whh in VGPRs
// (lane l holds k in [16l, 16l+16)).
// Barrier per group: arrival = one release STORE to slot[g*64+m] (no RMW);
// wait = wave 0 scans 64 slots with relaxed agent loads, then ONE acquire
// load (single cache-invalidate per step instead of per poll iteration).
__global__ __launch_bounds__(1024, 4) void k_gru(
    const float* __restrict__ Whh, const float* __restrict__ bhh,
    const float* __restrict__ CGI, const int* __restrict__ idx,
    float* __restrict__ H, int* __restrict__ slots)
{
  __shared__ float ghl[16][3][8];   // [dim-in-block][gate][batch-in-group]

  const int tid = threadIdx.x;
  const int w   = tid >> 6;          // wave 0..15
  const int l   = tid & 63;          // lane
  const int m   = blockIdx.x & 63;   // member within group
  const int g   = blockIdx.x >> 6;   // group 0..3
  const int d   = (m << 4) + w;      // this wave's dim

  // ---- gate rows of Whh into registers: 48 VGPR/lane
  float wr[16], wz[16], wn[16];
  {
    const float* p0 = Whh + (size_t)d * DIM + (l << 4);
    const float* p1 = Whh + (size_t)(DIM + d) * DIM + (l << 4);
    const float* p2 = Whh + (size_t)(2 * DIM + d) * DIM + (l << 4);
#pragma unroll
    for (int q = 0; q < 4; ++q) {
      float4 a = ((const float4*)p0)[q];
      wr[4*q+0] = a.x; wr[4*q+1] = a.y; wr[4*q+2] = a.z; wr[4*q+3] = a.w;
      float4 b = ((const float4*)p1)[q];
      wz[4*q+0] = b.x; wz[4*q+1] = b.y; wz[4*q+2] = b.z; wz[4*q+3] = b.w;
      float4 c = ((const float4*)p2)[q];
      wn[4*q+0] = c.x; wn[4*q+1] = c.y; wn[4*q+2] = c.z; wn[4*q+3] = c.w;
    }
  }
  const float bhr = bhh[d];
  const float bhz = bhh[DIM + d];
  const float bhn = bhh[2 * DIM + d];

  // epilogue thread state: thread (tid<128) owns (batch eb, dim 16m+ed) and
  // keeps its own h across timesteps in a register (no h_old reload).
  const int eb = tid >> 4;   // 0..7
  const int ed = tid & 15;   // 0..15
  float hprev = 0.f;

  int* myslots = slots + (g << 6);

  for (int t = 0; t < TLEN; ++t) {
    // ---- prefetch this step's codes + CGI gathers (constant data: safe and
    //      profitable to issue BEFORE the barrier wait)
    float ir = 0.f, iz = 0.f, inn = 0.f;
    if (tid < 128) {
      int code = idx[(size_t)((g << 3) + eb) * TLEN + t];
      const float* cgi = CGI + (size_t)code * (3 * DIM) + (m << 4) + ed;
      ir  = cgi[0];
      iz  = cgi[DIM];
      inn = cgi[2 * DIM];
    }

    if (t > 0) {
      if (tid < 64) {
        long guard = 0;
        while (__hip_atomic_load(&myslots[tid], __ATOMIC_RELAXED,
                                 __HIP_MEMORY_SCOPE_AGENT) < t) {
          __builtin_amdgcn_s_sleep(2);
          if (++guard > 4000000L) break;   // fail-safe: wrong > hung
        }
        // one acquire (cache-invalidate) after detection
        (void)__hip_atomic_load(&myslots[tid], __ATOMIC_ACQUIRE,
                                __HIP_MEMORY_SCOPE_AGENT);
      }
    }
    __syncthreads();   // S1: h[t-1] of the whole group now visible

    if (t > 0) {
      float4 bufA[4], bufB[4];
#define LOADH(buf, bb)                                                        \
      {                                                                       \
        const float* hp = H + ((size_t)((g << 3) + (bb)) * TLEN + (t - 1))    \
                              * DIM + (l << 4);                               \
        buf[0] = ((const float4*)hp)[0];                                      \
        buf[1] = ((const float4*)hp)[1];                                      \
        buf[2] = ((const float4*)hp)[2];                                      \
        buf[3] = ((const float4*)hp)[3];                                      \
      }
#define DOTRED(buf, bb)                                                       \
      {                                                                       \
        float ar = 0.f, az = 0.f, an = 0.f;                                   \
        _Pragma("unroll")                                                     \
        for (int q = 0; q < 4; ++q) {                                         \
          const float4 h4 = buf[q];                                           \
          ar += h4.x*wr[4*q+0] + h4.y*wr[4*q+1] + h4.z*wr[4*q+2] + h4.w*wr[4*q+3]; \
          az += h4.x*wz[4*q+0] + h4.y*wz[4*q+1] + h4.z*wz[4*q+2] + h4.w*wz[4*q+3]; \
          an += h4.x*wn[4*q+0] + h4.y*wn[4*q+1] + h4.z*wn[4*q+2] + h4.w*wn[4*q+3]; \
        }                                                                     \
        _Pragma("unroll")                                                     \
        for (int s = 1; s < 64; s <<= 1) {                                    \
          ar += __shfl_xor(ar, s);                                            \
          az += __shfl_xor(az, s);                                            \
          an += __shfl_xor(an, s);                                            \
        }                                                                     \
        if (l == 0) {                                                         \
          ghl[w][0][bb] = ar + bhr;                                           \
          ghl[w][1][bb] = az + bhz;                                           \
          ghl[w][2][bb] = an + bhn;                                           \
        }                                                                     \
      }
      // 2-deep software pipeline over the 8 group batches (static indices)
      LOADH(bufA, 0)
      LOADH(bufB, 1)  DOTRED(bufA, 0)
      LOADH(bufA, 2)  DOTRED(bufB, 1)
      LOADH(bufB, 3)  DOTRED(bufA, 2)
      LOADH(bufA, 4)  DOTRED(bufB, 3)
      LOADH(bufB, 5)  DOTRED(bufA, 4)
      LOADH(bufA, 6)  DOTRED(bufB, 5)
      LOADH(bufB, 7)  DOTRED(bufA, 6)
                      DOTRED(bufB, 7)
#undef LOADH
#undef DOTRED
    } else {
      if (l == 0) {
#pragma unroll
        for (int b = 0; b < 8; ++b) {
          ghl[w][0][b] = bhr; ghl[w][1][b] = bhz; ghl[w][2][b] = bhn;
        }
      }
    }
    __syncthreads();   // S2: ghl complete

    if (tid < 128) {
      float gr = ghl[ed][0][eb];
      float gz = ghl[ed][1][eb];
      float gn = ghl[ed][2][eb];
      float r = 1.f / (1.f + expf(-(ir + gr)));
      float z = 1.f / (1.f + expf(-(iz + gz)));
      float n = tanhf(inn + r * gn);
      float hn = (1.f - z) * n + z * hprev;
      __hip_atomic_store(
          &H[((size_t)((g << 3) + eb) * TLEN + t) * DIM + (m << 4) + ed], hn,
          __ATOMIC_RELAXED, __HIP_MEMORY_SCOPE_AGENT);
      hprev = hn;
    }
    __syncthreads();   // S3: compiler drains vmcnt before s_barrier -> stores done
    if (tid == 0)
      __hip_atomic_store(&myslots[m], t + 1, __ATOMIC_RELEASE,
                         __HIP_MEMORY_SCOPE_AGENT);
  }
}

// ---------------- CPC loss dots ----------------
__global__ __launch_bounds__(256) void k_loss(
    const float* __restrict__ Hp, const float* __restrict__ F,
    const int* __restrict__ nidx, float* __restrict__ cp_acc)
{
  int blk = blockIdx.x;
  int k, t;
  if (blk < 1023)      { k = 1; t = blk; }
  else if (blk < 2045) { k = 2; t = blk - 1023; }
  else                 { k = 3; t = blk - 2045; }
  const int tid = threadIdx.x;
  const int wv = tid >> 6, l = tid & 63;
  __shared__ float ssum[4];
  float lsum = 0.f;
  for (int bi = 0; bi < 8; ++bi) {
    int b = wv * 8 + bi;
    const float4* hp = (const float4*)(Hp + (size_t)(b * TLEN + t) * DIM);
    const float4* fp = (const float4*)(F + (size_t)(b * TLEN + t + k) * DIM);
    int nb = nidx[(k - 1) * TLEN * BATCH + t * BATCH + b];
    const float4* fn = (const float4*)(F + (size_t)(nb * TLEN + t) * DIM);
    float pos = 0.f, neg = 0.f;
#pragma unroll
    for (int c = 0; c < 4; ++c) {
      float4 h4 = hp[l + 64 * c];
      float4 p4 = fp[l + 64 * c];
      float4 n4 = fn[l + 64 * c];
      pos += h4.x*p4.x + h4.y*p4.y + h4.z*p4.z + h4.w*p4.w;
      neg += h4.x*n4.x + h4.y*n4.y + h4.z*n4.z + h4.w*n4.w;
    }
#pragma unroll
    for (int m = 1; m < 64; m <<= 1) {
      pos += __shfl_xor(pos, m);
      neg += __shfl_xor(neg, m);
    }
    if (l == 0) lsum += 1.f / (1.f + expf(neg - pos));
  }
  if (l == 0) ssum[wv] = lsum;
  __syncthreads();
  if (tid == 0) {
    float mean = (ssum[0] + ssum[1] + ssum[2] + ssum[3]) * (1.f / 32.f);
    atomicAdd(cp_acc, -logf(mean));
  }
}

__global__ void k_final(const float* __restrict__ sse, const float* __restrict__ cp,
                        float* __restrict__ out) {
  out[0] = cp[0] * (1.f / 3063.f) + 1.25f * sse[0] * (1.f / 33554432.f);
}

extern "C" void kernel_launch(void* const* d_in, const int* in_sizes, int n_in,
                              void* d_out, int out_size, void* d_ws, size_t ws_size,
                              hipStream_t stream)
{
  const float* F    = (const float*)d_in[0];
  const float* CB   = (const float*)d_in[1];
  const float* Wih  = (const float*)d_in[2];
  const float* Whh  = (const float*)d_in[3];
  const float* bih  = (const float*)d_in[4];
  const float* bhh  = (const float*)d_in[5];
  const float* Wp   = (const float*)d_in[6];
  const float* bp   = (const float*)d_in[7];
  const int*   nidx = (const int*)d_in[8];
  float* out = (float*)d_out;
  float* ws  = (float*)d_ws;

  hipMemsetAsync(d_ws, 0, 64, stream);   // sse, cp accumulators
  // sync slots for k_gru live in the (dead-until-GEMM2) Hp region: 256 ints
  hipMemsetAsync((void*)((char*)d_ws + (size_t)WS_HP * 4), 0, 1024, stream);

  k_norms<<<NCODE, 256, 0, stream>>>(CB, ws + WS_CC);
  k_quant<<<1024, 256, 0, stream>>>(F, CB, ws + WS_CC, out,
                                    out + OUT_IDX, (int*)(ws + WS_IDX), ws + 1);
  k_gemm_nt<64,128,16><<<dim3(3072/128, 256/64), 256, 0, stream>>>(
      CB, Wih, bih, ws + WS_CGI, 256, 3072, 1024);
  k_gru<<<256, 1024, 0, stream>>>(Whh, bhh, ws + WS_CGI,
                                  (const int*)(ws + WS_IDX), ws + WS_H,
                                  (int*)(ws + WS_HP));
  k_gemm_nt<64,128,16><<<dim3(1024/128, 32768/64), 256, 0, stream>>>(
      ws + WS_H, Wp, bp, ws + WS_HP, 32768, 1024, 1024);
  k_loss<<<3066, 256, 0, stream>>>(ws + WS_HP, F, nidx, ws + 2);
  k_final<<<1, 1, 0, stream>>>(ws + 1, ws + 2, out + OUT_TOT);
}